// Round 1
// baseline (1745.562 us; speedup 1.0000x reference)
//
#include <hip/hip_runtime.h>
#include <hip/hip_bf16.h>

typedef __attribute__((ext_vector_type(8))) short short8;
typedef __attribute__((ext_vector_type(4))) float f32x4;

#define CH 128
#define H 256
#define W 512
#define PH 258
#define PW 516
#define NTAPS 13
#define P_BYTES (PH * PW * CH * 2)   // 34,080,768

// ---------------- kernel 1: premask + cast weights -> Wt[13][oc][ic] bf16 ----
__global__ void premask_weights(const float* __restrict__ w,
                                __hip_bfloat16* __restrict__ Wt) {
    int idx = blockIdx.x * 256 + threadIdx.x;
    if (idx >= NTAPS * CH * CH) return;
    int t   = idx >> 14;          // /16384
    int rem = idx & 16383;
    int oc  = rem >> 7;
    int ic  = rem & 127;
    int ky  = t < 5 ? 0 : (t < 10 ? 1 : 2);
    int kx  = t - ky * 5;
    float v = w[(oc * CH + ic) * 25 + ky * 5 + kx];
    // center tap group-causal mask (HIDDEN=True: g_in <= g_out)
    if (t == 12 && ((ic >> 4) > (oc >> 4))) v = 0.f;
    Wt[idx] = __float2bfloat16(v);
}

// ------------- kernel 2: NCHW fp32 -> padded NHWC bf16 (one n) ---------------
// P layout: [PH=258][PW=516][CH=128] bf16; interior at rows 2..257, cols 2..513
__global__ void transpose_pad_kernel(const float* __restrict__ xn,
                                     __hip_bfloat16* __restrict__ P) {
    __shared__ float tile[32][33];
    int h  = blockIdx.y;
    int wt = blockIdx.x & 15;     // 16 w-tiles of 32
    int ct = blockIdx.x >> 4;     // 4 c-tiles of 32
    int tx = threadIdx.x & 31;
    int ty = threadIdx.x >> 5;    // 0..7
#pragma unroll
    for (int r = 0; r < 4; ++r) {
        int c = ct * 32 + ty + r * 8;
        tile[ty + r * 8][tx] = xn[(c * H + h) * W + wt * 32 + tx];  // coalesced read
    }
    __syncthreads();
#pragma unroll
    for (int r = 0; r < 4; ++r) {
        int wl = ty + r * 8;
        int c  = ct * 32 + tx;
        // coalesced write: 32 consecutive channels (64B)
        P[((h + 2) * PW + (wt * 32 + wl + 2)) * CH + c] =
            __float2bfloat16(tile[tx][wl]);
    }
}

// ------------- kernel 3: MFMA conv for one n --------------------------------
// Block: 128 oc x 128 pixels (one h row, 128 consecutive w).
// 4 waves in 2x2: wave covers 64 oc x 64 pixels = 4x4 frags of 16x16.
// A = Wt[t][oc][ic] (M=oc, K=ic), B = P patches (K=ic, N=pixel).
// D: col = lane&15 = pixel, row = 4*(lane>>4)+i = oc-within-frag.
__global__ __launch_bounds__(256)
void conv_mfma(const __hip_bfloat16* __restrict__ P,
               const __hip_bfloat16* __restrict__ Wt,
               const float* __restrict__ bias,
               const float* __restrict__ slope,
               float* __restrict__ outn) {
    int h    = blockIdx.y;
    int w0   = blockIdx.x << 7;       // 0,128,256,384
    int lane = threadIdx.x & 63;
    int wv   = threadIdx.x >> 6;
    int obase = (wv >> 1) * 64;       // oc half
    int pbase = (wv & 1) * 64;        // pixel half
    int l15  = lane & 15;
    int koff = (lane >> 4) * 8;       // k offset within 32-chunk

    f32x4 acc[4][4];
#pragma unroll
    for (int mi = 0; mi < 4; ++mi)
#pragma unroll
        for (int ni = 0; ni < 4; ++ni)
            acc[mi][ni] = (f32x4){0.f, 0.f, 0.f, 0.f};

    for (int t = 0; t < NTAPS; ++t) {
        int ky = t < 5 ? 0 : (t < 10 ? 1 : 2);
        int kx = t - ky * 5;
        const __hip_bfloat16* Wp = Wt + t * (CH * CH) + (obase + l15) * CH + koff;
        const __hip_bfloat16* Pp = P + ((h + ky) * PW + (w0 + kx + pbase + l15)) * CH + koff;
#pragma unroll
        for (int kc = 0; kc < 4; ++kc) {
            short8 a[4], b[4];
#pragma unroll
            for (int mi = 0; mi < 4; ++mi)
                a[mi] = *reinterpret_cast<const short8*>(Wp + mi * 16 * CH + kc * 32);
#pragma unroll
            for (int ni = 0; ni < 4; ++ni)
                b[ni] = *reinterpret_cast<const short8*>(Pp + ni * 16 * CH + kc * 32);
#pragma unroll
            for (int mi = 0; mi < 4; ++mi)
#pragma unroll
                for (int ni = 0; ni < 4; ++ni)
                    acc[mi][ni] = __builtin_amdgcn_mfma_f32_16x16x32_bf16(
                        a[mi], b[ni], acc[mi][ni], 0, 0, 0);
        }
    }

    // epilogue: bias + per-channel leaky relu, quarter-wave coalesced stores
#pragma unroll
    for (int mi = 0; mi < 4; ++mi) {
        int ocb = obase + mi * 16 + 4 * (lane >> 4);
        f32x4 b4 = *reinterpret_cast<const f32x4*>(bias + ocb);
        f32x4 s4 = *reinterpret_cast<const f32x4*>(slope + ocb);
#pragma unroll
        for (int i = 0; i < 4; ++i) {
            int oc = ocb + i;
            float* orow = outn + (oc * H + h) * W + w0;
#pragma unroll
            for (int ni = 0; ni < 4; ++ni) {
                float v = acc[mi][ni][i] + b4[i];
                v = v > 0.f ? v : s4[i] * v;
                orow[pbase + ni * 16 + l15] = v;
            }
        }
    }
}

extern "C" void kernel_launch(void* const* d_in, const int* in_sizes, int n_in,
                              void* d_out, int out_size, void* d_ws, size_t ws_size,
                              hipStream_t stream) {
    const float* x      = (const float*)d_in[0];
    const float* weight = (const float*)d_in[1];
    const float* bias   = (const float*)d_in[2];
    const float* slope  = (const float*)d_in[3];
    float* out = (float*)d_out;

    __hip_bfloat16* P  = (__hip_bfloat16*)d_ws;
    __hip_bfloat16* Wt = (__hip_bfloat16*)((char*)d_ws + P_BYTES);

    // zero the padded slab once (pads stay zero; interior overwritten per n)
    hipMemsetAsync(d_ws, 0, P_BYTES, stream);
    premask_weights<<<(NTAPS * CH * CH + 255) / 256, 256, 0, stream>>>(weight, Wt);

    for (int n = 0; n < 8; ++n) {
        const float* xn = x + (size_t)n * CH * H * W;
        float* on       = out + (size_t)n * CH * H * W;
        transpose_pad_kernel<<<dim3(64, 256), 256, 0, stream>>>(xn, P);
        conv_mfma<<<dim3(4, 256), 256, 0, stream>>>(P, Wt, bias, slope, on);
    }
}

// Round 3
// 850.408 us; speedup vs baseline: 2.0526x; 2.0526x over previous
//
#include <hip/hip_runtime.h>
#include <hip/hip_bf16.h>

typedef __attribute__((ext_vector_type(8))) short short8;
typedef __attribute__((ext_vector_type(4))) float f32x4;

#define CH 128
#define H 256
#define W 512
#define PH 258
#define PW 516
#define NTAPS 13
#define P_BYTES (PH * PW * CH * 2)   // 34,080,768

#define GLD_LDS16(g, l)                                                        \
  __builtin_amdgcn_global_load_lds(                                            \
      (const __attribute__((address_space(1))) void*)(g),                      \
      (__attribute__((address_space(3))) void*)(l), 16, 0, 0)

// ---- kernel 1: premask + cast weights into MFMA-fragment order -------------
// Wt2 element idx = fragIdx*512 + lane*8 + e, fragIdx = (t*8 + ob)*4 + kcg
// lane: oc = ob*16 + (lane&15), ic = kcg*32 + (lane>>4)*8 + e
__global__ void premask_weights(const float* __restrict__ w,
                                __hip_bfloat16* __restrict__ Wt2) {
    int idx  = blockIdx.x * 256 + threadIdx.x;   // exactly 13*8*4*512 = 212992
    int frag = idx >> 9;
    int r    = idx & 511;
    int l    = r >> 3;
    int e    = r & 7;
    int t    = frag >> 5;
    int ob   = (frag >> 2) & 7;
    int kcg  = frag & 3;
    int oc   = ob * 16 + (l & 15);
    int ic   = kcg * 32 + (l >> 4) * 8 + e;
    int ky   = t < 5 ? 0 : (t < 10 ? 1 : 2);
    int kx   = t - ky * 5;
    float v  = w[(oc * CH + ic) * 25 + ky * 5 + kx];
    if (t == 12 && ((ic >> 4) > (oc >> 4))) v = 0.f;   // group-causal center tap
    Wt2[idx] = __float2bfloat16(v);
}

// ---- kernel 2: NCHW fp32 -> padded NHWC bf16 (one n), vectorized stores ----
__global__ void transpose_pad_kernel(const float* __restrict__ xn,
                                     __hip_bfloat16* __restrict__ P) {
    __shared__ float tile[32][33];   // [c-local][w-local]
    int h  = blockIdx.y;
    int wt = blockIdx.x & 15;        // 16 w-tiles of 32
    int ct = blockIdx.x >> 4;        // 4 c-tiles of 32
    int tx = threadIdx.x & 31;
    int ty = threadIdx.x >> 5;       // 0..7
#pragma unroll
    for (int r = 0; r < 4; ++r) {
        int c = ct * 32 + ty + r * 8;
        tile[ty + r * 8][tx] = xn[(c * H + h) * W + wt * 32 + tx];  // coalesced
    }
    __syncthreads();
    // store: 8-B vector per thread, 64 B contiguous per pixel
    int wl = threadIdx.x >> 3;       // 0..31
    int cq = threadIdx.x & 7;        // 0..7 -> 4 channels
    union { ushort4 u; __hip_bfloat16 h[4]; } v;
    v.h[0] = __float2bfloat16(tile[cq * 4 + 0][wl]);
    v.h[1] = __float2bfloat16(tile[cq * 4 + 1][wl]);
    v.h[2] = __float2bfloat16(tile[cq * 4 + 2][wl]);
    v.h[3] = __float2bfloat16(tile[cq * 4 + 3][wl]);
    *reinterpret_cast<ushort4*>(
        (unsigned short*)P +
        ((size_t)(h + 2) * PW + (wt * 32 + wl + 2)) * CH + ct * 32 + cq * 4) = v.u;
}

// ---- kernel 3: MFMA conv, LDS-staged input, k-split ------------------------
// Block: 128 oc x 128 px (one h row). 4 waves 2x2: each 64 oc x 64 px.
// LDS tile: [3 rows][136 px][64 ch] bf16, 16-B chunks XOR-swizzled cc^=(px&7)
__global__ __launch_bounds__(256, 3)
void conv_mfma(const __hip_bfloat16* __restrict__ P,
               const __hip_bfloat16* __restrict__ Wt2,
               const float* __restrict__ bias,
               const float* __restrict__ slope,
               float* __restrict__ outn) {
    __shared__ short lds[3 * 136 * 64];   // 52,224 B -> 3 blocks/CU
    int h     = blockIdx.y;
    int w0    = blockIdx.x << 7;
    int tid   = threadIdx.x;
    int lane  = tid & 63;
    int wv    = tid >> 6;
    int l15   = lane & 15;
    int khi   = lane >> 4;
    int obf   = (wv >> 1) * 4;        // oc fragment base (0 or 4)
    int pbase = (wv & 1) * 64;        // pixel base (0 or 64)

    f32x4 acc[4][4];
#pragma unroll
    for (int mi = 0; mi < 4; ++mi)
#pragma unroll
        for (int ni = 0; ni < 4; ++ni)
            acc[mi][ni] = (f32x4){0.f, 0.f, 0.f, 0.f};

    const short* Wt2s = (const short*)Wt2;

    for (int kk = 0; kk < 2; ++kk) {
        // ---- stage: 51 wave-loads of 1 KB, round-robin over 4 waves --------
        {
            int pxl = lane >> 3;      // 0..7 within strip
            int cc  = lane & 7;
            for (int s = wv; s < 51; s += 4) {
                int rrow = (s >= 34) ? 2 : (s >= 17 ? 1 : 0);
                int s2   = s - rrow * 17;
                int pxs  = s2 * 8 + pxl;            // 0..135
                int pxc  = pxs < 132 ? pxs : 131;   // clamp halo (unused px)
                int ccs  = cc ^ (pxs & 7);          // pre-swizzled source
                const __hip_bfloat16* g =
                    P + ((size_t)(h + rrow) * PW + (w0 + pxc)) * CH + kk * 64 + ccs * 8;
                GLD_LDS16(g, (char*)lds + (rrow * 1088 + s2 * 64) * 16);
            }
        }
        __syncthreads();

        // ---- compute: 13 taps x 2 k-chunks x 16 MFMA -----------------------
        for (int t = 0; t < NTAPS; ++t) {
            int ky = t < 5 ? 0 : (t < 10 ? 1 : 2);
            int kx = t - ky * 5;
#pragma unroll
            for (int kc = 0; kc < 2; ++kc) {
                int kcg = kk * 2 + kc;
                const short* ap = Wt2s + (((t * 8 + obf) * 4 + kcg) << 9) + (lane << 3);
                int pxs0 = pbase + kx + l15;
                const short* bp = lds +
                    ((ky * 136 + pxs0) * 8 + ((kc * 4 + khi) ^ (pxs0 & 7))) * 8;
                short8 a[4], b[4];
#pragma unroll
                for (int mi = 0; mi < 4; ++mi)
                    a[mi] = *reinterpret_cast<const short8*>(ap + mi * 2048);
#pragma unroll
                for (int ni = 0; ni < 4; ++ni)
                    b[ni] = *reinterpret_cast<const short8*>(bp + ni * 1024);
#pragma unroll
                for (int mi = 0; mi < 4; ++mi)
#pragma unroll
                    for (int ni = 0; ni < 4; ++ni)
                        acc[mi][ni] = __builtin_amdgcn_mfma_f32_16x16x32_bf16(
                            a[mi], b[ni], acc[mi][ni], 0, 0, 0);
            }
        }
        __syncthreads();
    }

    // ---- epilogue: bias + per-channel leaky relu ----------------------------
#pragma unroll
    for (int mi = 0; mi < 4; ++mi) {
        int ocb = obf * 16 + mi * 16 + 4 * khi;
        f32x4 b4 = *reinterpret_cast<const f32x4*>(bias + ocb);
        f32x4 s4 = *reinterpret_cast<const f32x4*>(slope + ocb);
#pragma unroll
        for (int i = 0; i < 4; ++i) {
            float* orow = outn + ((ocb + i) * H + h) * W + w0;
#pragma unroll
            for (int ni = 0; ni < 4; ++ni) {
                float v = acc[mi][ni][i] + b4[i];
                v = v > 0.f ? v : s4[i] * v;
                orow[pbase + ni * 16 + l15] = v;
            }
        }
    }
}

extern "C" void kernel_launch(void* const* d_in, const int* in_sizes, int n_in,
                              void* d_out, int out_size, void* d_ws, size_t ws_size,
                              hipStream_t stream) {
    const float* x      = (const float*)d_in[0];
    const float* weight = (const float*)d_in[1];
    const float* bias   = (const float*)d_in[2];
    const float* slope  = (const float*)d_in[3];
    float* out = (float*)d_out;

    __hip_bfloat16* P   = (__hip_bfloat16*)d_ws;
    __hip_bfloat16* Wt2 = (__hip_bfloat16*)((char*)d_ws + P_BYTES);

    (void)hipMemsetAsync(d_ws, 0, P_BYTES, stream);   // zero pads once
    premask_weights<<<832, 256, 0, stream>>>(weight, Wt2);

    for (int n = 0; n < 8; ++n) {
        const float* xn = x + (size_t)n * CH * H * W;
        float* on       = out + (size_t)n * CH * H * W;
        transpose_pad_kernel<<<dim3(64, 256), 256, 0, stream>>>(xn, P);
        conv_mfma<<<dim3(4, 256), 256, 0, stream>>>(P, Wt2, bias, slope, on);
    }
}

// Round 4
// 745.617 us; speedup vs baseline: 2.3411x; 1.1405x over previous
//
#include <hip/hip_runtime.h>
#include <hip/hip_bf16.h>

typedef __attribute__((ext_vector_type(8))) short short8;
typedef __attribute__((ext_vector_type(4))) float f32x4;

#define CH 128
#define H 256
#define W 512
#define PH 258
#define PW 516
#define NTAPS 13
#define P_BYTES (PH * PW * CH * 2)   // 34,080,768

#define GLD_LDS16(g, l)                                                        \
  __builtin_amdgcn_global_load_lds(                                            \
      (const __attribute__((address_space(1))) void*)(g),                      \
      (__attribute__((address_space(3))) void*)(l), 16, 0, 0)

// ---- kernel 1: premask + cast weights into MFMA-fragment order -------------
// Wt2 element idx = fragIdx*512 + lane*8 + e, fragIdx = (t*8 + ob)*4 + kcg
// lane: oc = ob*16 + (lane&15), ic = kcg*32 + (lane>>4)*8 + e
__global__ void premask_weights(const float* __restrict__ w,
                                __hip_bfloat16* __restrict__ Wt2) {
    int idx  = blockIdx.x * 256 + threadIdx.x;   // exactly 13*8*4*512 = 212992
    int frag = idx >> 9;
    int r    = idx & 511;
    int l    = r >> 3;
    int e    = r & 7;
    int t    = frag >> 5;
    int ob   = (frag >> 2) & 7;
    int kcg  = frag & 3;
    int oc   = ob * 16 + (l & 15);
    int ic   = kcg * 32 + (l >> 4) * 8 + e;
    int ky   = t < 5 ? 0 : (t < 10 ? 1 : 2);
    int kx   = t - ky * 5;
    float v  = w[(oc * CH + ic) * 25 + ky * 5 + kx];
    if (t == 12 && ((ic >> 4) > (oc >> 4))) v = 0.f;   // group-causal center tap
    Wt2[idx] = __float2bfloat16(v);
}

// ---- kernel 2: NCHW fp32 -> padded NHWC bf16 (one n), vectorized stores ----
__global__ void transpose_pad_kernel(const float* __restrict__ xn,
                                     __hip_bfloat16* __restrict__ P) {
    __shared__ float tile[32][33];   // [c-local][w-local]
    int h  = blockIdx.y;
    int wt = blockIdx.x & 15;        // 16 w-tiles of 32
    int ct = blockIdx.x >> 4;        // 4 c-tiles of 32
    int tx = threadIdx.x & 31;
    int ty = threadIdx.x >> 5;       // 0..7
#pragma unroll
    for (int r = 0; r < 4; ++r) {
        int c = ct * 32 + ty + r * 8;
        tile[ty + r * 8][tx] = xn[(c * H + h) * W + wt * 32 + tx];  // coalesced
    }
    __syncthreads();
    // store: 8-B vector per thread, 64 B contiguous per pixel
    int wl = threadIdx.x >> 3;       // 0..31
    int cq = threadIdx.x & 7;        // 0..7 -> 4 channels
    union { ushort4 u; __hip_bfloat16 h[4]; } v;
    v.h[0] = __float2bfloat16(tile[cq * 4 + 0][wl]);
    v.h[1] = __float2bfloat16(tile[cq * 4 + 1][wl]);
    v.h[2] = __float2bfloat16(tile[cq * 4 + 2][wl]);
    v.h[3] = __float2bfloat16(tile[cq * 4 + 3][wl]);
    *reinterpret_cast<ushort4*>(
        (unsigned short*)P +
        ((size_t)(h + 2) * PW + (wt * 32 + wl + 2)) * CH + ct * 32 + cq * 4) = v.u;
}

// ---- kernel 3: MFMA conv, LDS-staged input, 4-way k-split ------------------
// Block: 128 oc x 256 px (one h row). 4 waves 2x2: each 64 oc x 128 px.
// LDS tile per k-chunk: [3 rows][264 px][32 ch] bf16.
// 16-B granule g = (row*264+px)*4 + chunk, swizzle chunk ^= (px&3).
__global__ __launch_bounds__(256, 2)
void conv_mfma(const __hip_bfloat16* __restrict__ P,
               const __hip_bfloat16* __restrict__ Wt2,
               const float* __restrict__ bias,
               const float* __restrict__ slope,
               float* __restrict__ outn) {
    __shared__ short lds[3 * 264 * 32 + 256];   // 51,200 B -> 2 blocks/CU (VGPR-bound)
    int h     = blockIdx.y;
    int w0    = blockIdx.x << 8;      // 0 or 256
    int tid   = threadIdx.x;
    int lane  = tid & 63;
    int wv    = tid >> 6;
    int l15   = lane & 15;
    int khi   = lane >> 4;            // 0..3 -> k-offset khi*8 within 32-chunk
    int obf   = (wv >> 1) * 4;        // oc fragment base (0 or 4) -> oc 0/64
    int pbase = (wv & 1) * 128;       // pixel base (0 or 128)

    f32x4 acc[4][8];
#pragma unroll
    for (int mi = 0; mi < 4; ++mi)
#pragma unroll
        for (int ni = 0; ni < 8; ++ni)
            acc[mi][ni] = (f32x4){0.f, 0.f, 0.f, 0.f};

    const short* Wt2s = (const short*)Wt2;

    for (int kk = 0; kk < 4; ++kk) {
        // ---- stage k-chunk: 50 wave-loads of 1 KB, round-robin over 4 waves
        {
            for (int s = wv; s < 50; s += 4) {
                int g64  = (s << 6) + lane;               // granule index
                int row  = (g64 >= 2112 ? 1 : 0) + (g64 >= 1056 ? 1 : 0);
                int rem  = g64 - row * 1056;
                int px   = rem >> 2;                      // 0..271 (tail junk)
                int chk  = rem & 3;
                int ccs  = chk ^ (px & 3);                // inverse-swizzled src
                int pxc  = px < 260 ? px : 259;           // clamp (slots >259 unused)
                const __hip_bfloat16* g =
                    P + ((size_t)(h + row) * PW + (w0 + pxc)) * CH + kk * 32 + ccs * 8;
                GLD_LDS16(g, (char*)lds + (s << 10));     // linear dest, +lane*16 HW
            }
        }
        __syncthreads();

        // ---- compute: 13 taps x 32 MFMA -------------------------------------
        for (int t = 0; t < NTAPS; ++t) {
            int ky = t < 5 ? 0 : (t < 10 ? 1 : 2);
            int kx = t - ky * 5;
            const short* ap = Wt2s + (((t * 8 + obf) * 4 + kk) << 9) + (lane << 3);
            int pxb = pbase + kx + l15;                   // LDS px slot
            const short* bp = lds + ((((ky * 264 + pxb) << 2) +
                                      (khi ^ (pxb & 3))) << 3);
            short8 a[4], b[8];
#pragma unroll
            for (int mi = 0; mi < 4; ++mi)
                a[mi] = *reinterpret_cast<const short8*>(ap + mi * 2048);
#pragma unroll
            for (int ni = 0; ni < 8; ++ni)
                b[ni] = *reinterpret_cast<const short8*>(bp + ni * 512);
#pragma unroll
            for (int mi = 0; mi < 4; ++mi)
#pragma unroll
                for (int ni = 0; ni < 8; ++ni)
                    acc[mi][ni] = __builtin_amdgcn_mfma_f32_16x16x32_bf16(
                        a[mi], b[ni], acc[mi][ni], 0, 0, 0);
        }
        __syncthreads();
    }

    // ---- epilogue: bias + per-channel leaky relu ----------------------------
#pragma unroll
    for (int mi = 0; mi < 4; ++mi) {
        int ocb = obf * 16 + mi * 16 + 4 * khi;
        f32x4 b4 = *reinterpret_cast<const f32x4*>(bias + ocb);
        f32x4 s4 = *reinterpret_cast<const f32x4*>(slope + ocb);
#pragma unroll
        for (int i = 0; i < 4; ++i) {
            float* orow = outn + ((ocb + i) * H + h) * W + w0;
#pragma unroll
            for (int ni = 0; ni < 8; ++ni) {
                float v = acc[mi][ni][i] + b4[i];
                v = v > 0.f ? v : s4[i] * v;
                orow[pbase + ni * 16 + l15] = v;
            }
        }
    }
}

extern "C" void kernel_launch(void* const* d_in, const int* in_sizes, int n_in,
                              void* d_out, int out_size, void* d_ws, size_t ws_size,
                              hipStream_t stream) {
    const float* x      = (const float*)d_in[0];
    const float* weight = (const float*)d_in[1];
    const float* bias   = (const float*)d_in[2];
    const float* slope  = (const float*)d_in[3];
    float* out = (float*)d_out;

    __hip_bfloat16* P   = (__hip_bfloat16*)d_ws;
    __hip_bfloat16* Wt2 = (__hip_bfloat16*)((char*)d_ws + P_BYTES);

    (void)hipMemsetAsync(d_ws, 0, P_BYTES, stream);   // zero pads once
    premask_weights<<<832, 256, 0, stream>>>(weight, Wt2);

    for (int n = 0; n < 8; ++n) {
        const float* xn = x + (size_t)n * CH * H * W;
        float* on       = out + (size_t)n * CH * H * W;
        transpose_pad_kernel<<<dim3(64, 256), 256, 0, stream>>>(xn, P);
        conv_mfma<<<dim3(2, 256), 256, 0, stream>>>(P, Wt2, bias, slope, on);
    }
}

// Round 5
// 647.143 us; speedup vs baseline: 2.6973x; 1.1522x over previous
//
#include <hip/hip_runtime.h>
#include <hip/hip_bf16.h>

typedef __attribute__((ext_vector_type(8))) short short8;
typedef __attribute__((ext_vector_type(4))) float f32x4;

#define CH 128
#define H 256
#define W 512
#define PH 258
#define PW 516
#define NTAPS 13
#define P_BYTES (PH * PW * CH * 2)   // 34,080,768

// per-chunk LDS buffer: 4 rows x 136 px-slots x 4 granules(16B) + pad = 2304 granules
#define GRAN_PER_ROW 544             // 136 * 4
#define BUF_GRAN 2304                // 36 wave-loads x 64
#define BUF_SHORTS (BUF_GRAN * 8)    // 18432 shorts = 36,864 B

#define GLD_LDS16(g, l)                                                        \
  __builtin_amdgcn_global_load_lds(                                            \
      (const __attribute__((address_space(1))) void*)(g),                      \
      (__attribute__((address_space(3))) void*)(l), 16, 0, 0)

// ---- kernel 1: premask + cast weights into MFMA-fragment order -------------
// Wt2 element idx = fragIdx*512 + lane*8 + e, fragIdx = (t*8 + ob)*4 + kcg
// lane: oc = ob*16 + (lane&15), ic = kcg*32 + (lane>>4)*8 + e
__global__ void premask_weights(const float* __restrict__ w,
                                __hip_bfloat16* __restrict__ Wt2) {
    int idx  = blockIdx.x * 256 + threadIdx.x;   // exactly 13*8*4*512 = 212992
    int frag = idx >> 9;
    int r    = idx & 511;
    int l    = r >> 3;
    int e    = r & 7;
    int t    = frag >> 5;
    int ob   = (frag >> 2) & 7;
    int kcg  = frag & 3;
    int oc   = ob * 16 + (l & 15);
    int ic   = kcg * 32 + (l >> 4) * 8 + e;
    int ky   = t < 5 ? 0 : (t < 10 ? 1 : 2);
    int kx   = t - ky * 5;
    float v  = w[(oc * CH + ic) * 25 + ky * 5 + kx];
    if (t == 12 && ((ic >> 4) > (oc >> 4))) v = 0.f;   // group-causal center tap
    Wt2[idx] = __float2bfloat16(v);
}

// ---- kernel 2: NCHW fp32 -> padded NHWC bf16 (one n), vectorized stores ----
__global__ void transpose_pad_kernel(const float* __restrict__ xn,
                                     __hip_bfloat16* __restrict__ P) {
    __shared__ float tile[32][33];   // [c-local][w-local]
    int h  = blockIdx.y;
    int wt = blockIdx.x & 15;        // 16 w-tiles of 32
    int ct = blockIdx.x >> 4;        // 4 c-tiles of 32
    int tx = threadIdx.x & 31;
    int ty = threadIdx.x >> 5;       // 0..7
#pragma unroll
    for (int r = 0; r < 4; ++r) {
        int c = ct * 32 + ty + r * 8;
        tile[ty + r * 8][tx] = xn[(c * H + h) * W + wt * 32 + tx];  // coalesced
    }
    __syncthreads();
    // store: 8-B vector per thread, 64 B contiguous per pixel
    int wl = threadIdx.x >> 3;       // 0..31
    int cq = threadIdx.x & 7;        // 0..7 -> 4 channels
    union { ushort4 u; __hip_bfloat16 h[4]; } v;
    v.h[0] = __float2bfloat16(tile[cq * 4 + 0][wl]);
    v.h[1] = __float2bfloat16(tile[cq * 4 + 1][wl]);
    v.h[2] = __float2bfloat16(tile[cq * 4 + 2][wl]);
    v.h[3] = __float2bfloat16(tile[cq * 4 + 3][wl]);
    *reinterpret_cast<ushort4*>(
        (unsigned short*)P +
        ((size_t)(h + 2) * PW + (wt * 32 + wl + 2)) * CH + ct * 32 + cq * 4) = v.u;
}

// ---- kernel 3: MFMA conv, double-buffered LDS pipeline ---------------------
// Block: 128 oc x 2h x 128 w. 4 waves: wv>>1 = oc half, wv&1 = output row.
// Per-chunk LDS tile: [4 rows][136 px][32 ch] bf16, granule swizzle chk^=(px&3).
// Pipeline: issue stage(kk+1) -> compute(kk) -> barrier (drains prefetch).
__global__ __launch_bounds__(256, 2)
void conv_mfma(const __hip_bfloat16* __restrict__ P,
               const __hip_bfloat16* __restrict__ Wt2,
               const float* __restrict__ bias,
               const float* __restrict__ slope,
               float* __restrict__ outn) {
    __shared__ short lds[2 * BUF_SHORTS];   // 73,728 B -> 2 blocks/CU
    int h0    = blockIdx.y << 1;
    int w0    = blockIdx.x << 7;
    int tid   = threadIdx.x;
    int lane  = tid & 63;
    int wv    = tid >> 6;
    int l15   = lane & 15;
    int khi   = lane >> 4;            // 0..3
    int obf   = (wv >> 1) * 4;        // oc fragment base (0 or 4)
    int hsel  = wv & 1;               // which output row this wave owns

    f32x4 acc[4][8];
#pragma unroll
    for (int mi = 0; mi < 4; ++mi)
#pragma unroll
        for (int ni = 0; ni < 8; ++ni)
            acc[mi][ni] = (f32x4){0.f, 0.f, 0.f, 0.f};

    const short* Wt2s = (const short*)Wt2;

    // ---- stage chunk kk into buffer b: 36 wave-loads of 1 KB ---------------
    auto stage = [&](int kk, int b) {
#pragma unroll
        for (int i = 0; i < 9; ++i) {
            int s    = wv + i * 4;              // 0..35 (wave-uniform)
            int g64  = (s << 6) + lane;         // granule 0..2303
            int row  = (g64 >= 544) + (g64 >= 1088) + (g64 >= 1632) + (g64 >= 2176);
            int rem  = g64 - row * GRAN_PER_ROW;
            int px   = rem >> 2;
            int chk  = rem & 3;
            int rowc = row < 4 ? row : 3;       // pad granules -> safe addr
            int pxc  = px < 132 ? px : 131;     // clamp unused slots
            int ccs  = chk ^ (px & 3);          // inverse-swizzled source
            const __hip_bfloat16* g =
                P + ((size_t)(h0 + rowc) * PW + (w0 + pxc)) * CH + kk * 32 + ccs * 8;
            GLD_LDS16(g, (char*)lds + b * (BUF_SHORTS * 2) + (s << 10));
        }
    };

    stage(0, 0);
    __syncthreads();

    for (int kk = 0; kk < 4; ++kk) {
        int cur = kk & 1;
        if (kk < 3) stage(kk + 1, cur ^ 1);     // prefetch next chunk

        const short* bbase = lds + cur * BUF_SHORTS;
        for (int t = 0; t < NTAPS; ++t) {
            int ky  = t < 5 ? 0 : (t < 10 ? 1 : 2);
            int kx  = t - ky * 5;
            int row = hsel + ky;                // 0..3
            const short* ap = Wt2s + (((t * 8 + obf) * 4 + kk) << 9) + (lane << 3);
            int pxb = kx + l15;
            const short* bp = bbase +
                (((row * 136 + pxb) * 4 + (khi ^ (pxb & 3))) << 3);
            short8 a[4], b[8];
#pragma unroll
            for (int mi = 0; mi < 4; ++mi)
                a[mi] = *reinterpret_cast<const short8*>(ap + mi * 2048);
#pragma unroll
            for (int ni = 0; ni < 8; ++ni)
                b[ni] = *reinterpret_cast<const short8*>(bp + ni * 512);
            __builtin_amdgcn_s_setprio(1);
#pragma unroll
            for (int mi = 0; mi < 4; ++mi)
#pragma unroll
                for (int ni = 0; ni < 8; ++ni)
                    acc[mi][ni] = __builtin_amdgcn_mfma_f32_16x16x32_bf16(
                        a[mi], b[ni], acc[mi][ni], 0, 0, 0);
            __builtin_amdgcn_s_setprio(0);
        }
        __syncthreads();   // drains prefetch (vmcnt0) + protects buf reuse
    }

    // ---- epilogue: bias + per-channel leaky relu ----------------------------
    int hrow = h0 + hsel;
#pragma unroll
    for (int mi = 0; mi < 4; ++mi) {
        int ocb = obf * 16 + mi * 16 + 4 * khi;
        f32x4 b4 = *reinterpret_cast<const f32x4*>(bias + ocb);
        f32x4 s4 = *reinterpret_cast<const f32x4*>(slope + ocb);
#pragma unroll
        for (int i = 0; i < 4; ++i) {
            float* orow = outn + ((ocb + i) * H + hrow) * W + w0;
#pragma unroll
            for (int ni = 0; ni < 8; ++ni) {
                float v = acc[mi][ni][i] + b4[i];
                v = v > 0.f ? v : s4[i] * v;
                orow[ni * 16 + l15] = v;
            }
        }
    }
}

extern "C" void kernel_launch(void* const* d_in, const int* in_sizes, int n_in,
                              void* d_out, int out_size, void* d_ws, size_t ws_size,
                              hipStream_t stream) {
    const float* x      = (const float*)d_in[0];
    const float* weight = (const float*)d_in[1];
    const float* bias   = (const float*)d_in[2];
    const float* slope  = (const float*)d_in[3];
    float* out = (float*)d_out;

    __hip_bfloat16* P   = (__hip_bfloat16*)d_ws;
    __hip_bfloat16* Wt2 = (__hip_bfloat16*)((char*)d_ws + P_BYTES);

    (void)hipMemsetAsync(d_ws, 0, P_BYTES, stream);   // zero pads once
    premask_weights<<<832, 256, 0, stream>>>(weight, Wt2);

    for (int n = 0; n < 8; ++n) {
        const float* xn = x + (size_t)n * CH * H * W;
        float* on       = out + (size_t)n * CH * H * W;
        transpose_pad_kernel<<<dim3(64, 256), 256, 0, stream>>>(xn, P);
        conv_mfma<<<dim3(4, 128), 256, 0, stream>>>(P, Wt2, bias, slope, on);
    }
}